// Round 9
// baseline (381.019 us; speedup 1.0000x reference)
//
#include <hip/hip_runtime.h>
#include <hip/hip_bf16.h>
#include <cstdint>

#define AS1 __attribute__((address_space(1)))
#define AS3 __attribute__((address_space(3)))

typedef __attribute__((ext_vector_type(8))) short short8x;   // 8 bf16 (4 VGPRs)
typedef __attribute__((ext_vector_type(4))) float f32x4;     // MFMA C/D

static constexpr int T    = 4096;
static constexpr int HD   = 1024;
static constexpr int FD   = 4096;
static constexpr int NE   = 8;
static constexpr int P    = T * 2;
static constexpr int PPAD = P + 128;
static constexpr int MAXT = P / 128 + NE;   // 72 (128-row tiles), % 8 == 0
static constexpr int RTB  = 16;
static constexpr int RNB  = T / RTB;

struct TileDesc { int e; int start; int rows; int pad; };

__device__ __forceinline__ uint16_t f2bf(float f) {
  uint32_t u = __builtin_bit_cast(uint32_t, f);
  u += 0x7FFFu + ((u >> 16) & 1u);
  return (uint16_t)(u >> 16);
}
__device__ __forceinline__ float bf2f(uint16_t b) {
  uint32_t u = ((uint32_t)b) << 16;
  return __builtin_bit_cast(float, u);
}
__device__ __forceinline__ void gload_lds16(const void* g, void* l) {
  __builtin_amdgcn_global_load_lds((const AS1 uint32_t*)g, (AS3 uint32_t*)l, 16, 0, 0);
}

// ---------------- x fp32 -> bf16 ----------------
__global__ __launch_bounds__(256) void cvt_x_kernel(const float* __restrict__ x,
                                                    uint16_t* __restrict__ xb) {
  size_t i = ((size_t)blockIdx.x * 256 + threadIdx.x) * 4;
  float4 v = *(const float4*)&x[i];
  ushort4 o;
  o.x = f2bf(v.x); o.y = f2bf(v.y); o.z = f2bf(v.z); o.w = f2bf(v.w);
  *(ushort4*)&xb[i] = o;
}

// ------------- transpose + cvt: in [z][R][C] f32 -> out [z][C][R] bf16 -------------
__global__ __launch_bounds__(256) void transpose_cvt_kernel(
    const float* __restrict__ in, uint16_t* __restrict__ out, int R, int C) {
  __shared__ float tile[64][65];
  int z = blockIdx.z;
  const float* inp = in + (size_t)z * R * C;
  uint16_t* outp = out + (size_t)z * R * C;
  int r0 = blockIdx.y * 64, c0 = blockIdx.x * 64;
  int tid = threadIdx.x;
  int lr = tid >> 4;
  int lc4 = (tid & 15) * 4;
#pragma unroll
  for (int p = 0; p < 4; ++p) {
    float4 v = *(const float4*)&inp[(size_t)(r0 + lr + p * 16) * C + c0 + lc4];
    tile[lr + p * 16][lc4 + 0] = v.x;
    tile[lr + p * 16][lc4 + 1] = v.y;
    tile[lr + p * 16][lc4 + 2] = v.z;
    tile[lr + p * 16][lc4 + 3] = v.w;
  }
  __syncthreads();
#pragma unroll
  for (int p = 0; p < 4; ++p) {
    int c = lr + p * 16;
    ushort4 o;
    o.x = f2bf(tile[lc4 + 0][c]);
    o.y = f2bf(tile[lc4 + 1][c]);
    o.z = f2bf(tile[lc4 + 2][c]);
    o.w = f2bf(tile[lc4 + 3][c]);
    *(ushort4*)&outp[(size_t)(c0 + c) * R + r0 + lc4] = o;
  }
}

// ---------------- router ----------------
__global__ __launch_bounds__(256) void router_kernel(
    const float* __restrict__ x, const float* __restrict__ gate_w,
    int* __restrict__ topk_idx, float* __restrict__ topk_w,
    float* __restrict__ part_sums, int* __restrict__ part_counts) {
  __shared__ float g[NE * HD];
  __shared__ float ls[NE];
  __shared__ int   lc[NE];
  int tid = threadIdx.x;
  for (int i = tid; i < NE * HD; i += 256)
    g[(i & 7) * HD + (i >> 3)] = gate_w[i];
  if (tid < NE) { ls[tid] = 0.f; lc[tid] = 0; }
  __syncthreads();
  int wave = tid >> 6, lane = tid & 63;
  float psum[NE];
#pragma unroll
  for (int e = 0; e < NE; ++e) psum[e] = 0.f;

  for (int tt = 0; tt < RTB / 4; ++tt) {
    int t = blockIdx.x * RTB + wave * (RTB / 4) + tt;
    const float* xr = x + (size_t)t * HD;
    float acc[NE];
#pragma unroll
    for (int e = 0; e < NE; ++e) acc[e] = 0.f;
    for (int i = 0; i < HD / 64; ++i) {
      float xv = xr[lane + i * 64];
#pragma unroll
      for (int e = 0; e < NE; ++e) acc[e] += xv * g[e * HD + lane + i * 64];
    }
#pragma unroll
    for (int off = 32; off > 0; off >>= 1)
#pragma unroll
      for (int e = 0; e < NE; ++e) acc[e] += __shfl_down(acc[e], off);
    if (lane == 0) {
      float m = acc[0];
#pragma unroll
      for (int e = 1; e < NE; ++e) m = fmaxf(m, acc[e]);
      float p[NE], s = 0.f;
#pragma unroll
      for (int e = 0; e < NE; ++e) { p[e] = expf(acc[e] - m); s += p[e]; }
      float inv = 1.f / s;
#pragma unroll
      for (int e = 0; e < NE; ++e) { p[e] *= inv; psum[e] += p[e]; }
      int i0 = 0;
#pragma unroll
      for (int e = 1; e < NE; ++e) if (p[e] > p[i0]) i0 = e;
      int i1 = (i0 == 0) ? 1 : 0;
#pragma unroll
      for (int e = 0; e < NE; ++e) if (e != i0 && e != i1 && p[e] > p[i1]) i1 = e;
      float wsum = p[i0] + p[i1];
      topk_idx[t * 2] = i0; topk_idx[t * 2 + 1] = i1;
      topk_w[t * 2] = p[i0] / wsum; topk_w[t * 2 + 1] = p[i1] / wsum;
      atomicAdd(&lc[i0], 1); atomicAdd(&lc[i1], 1);
    }
  }
  if (lane == 0)
#pragma unroll
    for (int e = 0; e < NE; ++e) atomicAdd(&ls[e], psum[e]);
  __syncthreads();
  if (tid < NE) {
    part_sums[blockIdx.x * NE + tid]   = ls[tid];
    part_counts[blockIdx.x * NE + tid] = lc[tid];
  }
}

// ---------------- finalize ----------------
__global__ __launch_bounds__(64) void finalize_kernel(
    const int* __restrict__ part_counts, const float* __restrict__ part_sums,
    int* __restrict__ offsets, TileDesc* __restrict__ desc,
    int* __restrict__ ntiles, float* __restrict__ aux_out) {
  __shared__ int   csh[NE];
  __shared__ float ssh[NE];
  int tid = threadIdx.x;
  if (tid < NE) {
    int c = 0; float s = 0.f;
    for (int b = 0; b < RNB; ++b) {
      c += part_counts[b * NE + tid];
      s += part_sums[b * NE + tid];
    }
    csh[tid] = c; ssh[tid] = s;
  }
  __syncthreads();
  if (tid == 0) {
    int off = 0, nt = 0;
    for (int e = 0; e < NE; ++e) {
      offsets[e] = off;
      int c = csh[e];
      for (int i = 0; i < c; i += 128) {
        int rows = c - i; if (rows > 128) rows = 128;
        desc[nt].e = e; desc[nt].start = off + i; desc[nt].rows = rows; desc[nt].pad = 0;
        nt++;
      }
      off += c;
    }
    *ntiles = nt;
    float aux = 0.f;
    for (int e = 0; e < NE; ++e) {
      float mean = ssh[e] / (float)T;
      aux += mean * mean;
    }
    *aux_out = (float)NE * aux;
  }
}

// ---------------- scatter ----------------
__global__ __launch_bounds__(256) void scatter_kernel(
    const int* __restrict__ topk_idx, const int* __restrict__ offsets,
    int* __restrict__ fill, int* __restrict__ pair_tok, int* __restrict__ tok_pos) {
  int t = blockIdx.x * 256 + threadIdx.x;
  int lane = threadIdx.x & 63;
  unsigned long long below = (lane == 63) ? ~0ull >> 1
                                          : ((1ull << (lane + 1)) - 1) >> 1;
#pragma unroll
  for (int k = 0; k < 2; ++k) {
    int e = topk_idx[t * 2 + k];
    int pos = 0;
    for (int ex = 0; ex < NE; ++ex) {
      unsigned long long m = __ballot(e == ex);
      if (e == ex) {
        int leader = __ffsll((long long)m) - 1;
        int cnt = __popcll(m);
        int base = 0;
        if (lane == leader) base = atomicAdd(&fill[ex], cnt);
        base = __shfl(base, leader);
        pos = base + __popcll(m & below);
      }
    }
    int pp = offsets[e] + pos;
    pair_tok[pp] = t;
    tok_pos[t * 2 + k] = pp;
  }
}

// ---------------- MFMA GEMM: R8 structure + LDS swizzle + optional K-split ----------------
// C[rows, 0:ND] += A[rows, kOff:kOff+KLEN] * Bw[e][ND, KSTRIDE]^T slice (+bias at kh==0)
// Swizzle: LDS slot s of row r holds source 16B-slot s ^ (r&3) ^ ((r>>2)&3)
// -> 16-row fragment reads spread over all 8 bank positions, 2 lanes each (free).
// EPI=0: gather rows via pair_tok, relu, bf16 out, KH=1.
// EPI=1: contiguous rows, fp32 out at Cout + kh*P*ND, bias only in kh==0 half.
template <int KSTRIDE, int KLEN, int ND, int NBG, int KH, int EPI>
__global__ __launch_bounds__(256) void moe_gemm(
    const uint16_t* __restrict__ Abase, const int* __restrict__ pair_tok,
    const uint16_t* __restrict__ Bw, const float* __restrict__ bias,
    void* __restrict__ CoutV, const TileDesc* __restrict__ desc,
    const int* __restrict__ ntiles) {
  constexpr int SM = MAXT / 8;      // 9 mt-tiles per XCD

  int orig = blockIdx.x;
  int xcd = orig & 7, local = orig >> 3;
  int kh  = local % KH;
  int l2  = local / KH;
  int nbq = l2 / (SM * NBG);
  int rem = l2 % (SM * NBG);
  int mt  = xcd * SM + rem / NBG;
  int nb  = nbq * NBG + rem % NBG;
  if (mt >= *ntiles) return;
  TileDesc d = desc[mt];
  const int kOff = kh * KLEN;

  __shared__ uint16_t As[128 * 32];
  __shared__ uint16_t Bs[128 * 32];
  __shared__ int rowA[128];

  int tid = threadIdx.x, lane = tid & 63, wave = tid >> 6;
  int wm = wave >> 1, wn = wave & 1;

  int idx0 = wave * 128 + lane;        // (wave*2+0)*64 + lane
  int ar0 = idx0 >> 2, kc0 = idx0 & 3; // ar1 = ar0+16 (same &3, same >>2&3), kc1 = kc0
  int ar1 = ar0 + 16;
  int fsw = (ar0 & 3) ^ ((ar0 >> 2) & 3);
  int scol = (kc0 ^ fsw) * 8;          // pre-swizzled source 16B-slot

  int ra0, ra1;
  if constexpr (EPI == 0) {
    if (tid < 128) rowA[tid] = (tid < d.rows) ? pair_tok[d.start + tid] : 0;
    __syncthreads();
    ra0 = rowA[ar0]; ra1 = rowA[ar1];
  } else {
    ra0 = d.start + ar0; ra1 = d.start + ar1;
  }

  const uint16_t* Bbase = Bw + ((size_t)d.e * ND + (size_t)nb * 128) * KSTRIDE + kOff;
  const uint16_t* Ar0 = Abase + (size_t)ra0 * KSTRIDE + kOff + scol;
  const uint16_t* Ar1 = Abase + (size_t)ra1 * KSTRIDE + kOff + scol;
  const uint16_t* Br0 = Bbase + (size_t)ar0 * KSTRIDE + scol;
  const uint16_t* Br1 = Bbase + (size_t)ar1 * KSTRIDE + scol;

  f32x4 acc[4][4];
#pragma unroll
  for (int i = 0; i < 4; ++i)
#pragma unroll
    for (int j = 0; j < 4; ++j) acc[i][j] = (f32x4){0.f, 0.f, 0.f, 0.f};

  // fragment read offset: slot = (lane>>4) ^ f(row); f(row) = (lane&3) ^ ((lane>>2)&3)
  int swr = (((lane >> 4) ^ (lane & 3) ^ ((lane >> 2) & 3)) << 3);
  int l15 = lane & 15;

  for (int kt = 0; kt < KLEN / 32; ++kt) {
    if (kt) __syncthreads();
    int kb = kt * 32;
    gload_lds16(Ar0 + kb, &As[(wave * 2 + 0) * 512]);
    gload_lds16(Ar1 + kb, &As[(wave * 2 + 1) * 512]);
    gload_lds16(Br0 + kb, &Bs[(wave * 2 + 0) * 512]);
    gload_lds16(Br1 + kb, &Bs[(wave * 2 + 1) * 512]);
    __syncthreads();

    short8x af[4], bfr[4];
#pragma unroll
    for (int i = 0; i < 4; ++i)
      af[i] = *(const short8x*)&As[(wm * 64 + i * 16 + l15) * 32 + swr];
#pragma unroll
    for (int j = 0; j < 4; ++j)
      bfr[j] = *(const short8x*)&Bs[(wn * 64 + j * 16 + l15) * 32 + swr];
#pragma unroll
    for (int i = 0; i < 4; ++i)
#pragma unroll
      for (int j = 0; j < 4; ++j)
        acc[i][j] = __builtin_amdgcn_mfma_f32_16x16x32_bf16(af[i], bfr[j], acc[i][j], 0, 0, 0);
  }

  // epilogue: C/D layout col=lane&15, row=(lane>>4)*4+q  [measured m89]
  int rq = (lane >> 4) * 4;
  int cl = lane & 15;
#pragma unroll
  for (int i = 0; i < 4; ++i) {
    int rb = wm * 64 + i * 16 + rq;
#pragma unroll
    for (int j = 0; j < 4; ++j) {
      int col = nb * 128 + wn * 64 + j * 16 + cl;
      float bv = (EPI == 1 && kh != 0) ? 0.f : bias[d.e * ND + col];
#pragma unroll
      for (int q = 0; q < 4; ++q) {
        int r = rb + q;
        if (r < d.rows) {
          float v = acc[i][j][q] + bv;
          if constexpr (EPI == 0) {
            v = fmaxf(v, 0.f);
            ((uint16_t*)CoutV)[(size_t)(d.start + r) * ND + col] = f2bf(v);
          } else {
            ((float*)CoutV)[(size_t)kh * P * ND + (size_t)(d.start + r) * ND + col] = v;
          }
        }
      }
    }
  }
}

// ---------------- combine: out[t] = w0*(po0[p0]+po1[p0]) + w1*(po0[p1]+po1[p1]) ----------------
__global__ __launch_bounds__(256) void combine_kernel(
    const float* __restrict__ po, const int* __restrict__ tok_pos,
    const float* __restrict__ topk_w, float* __restrict__ out) {
  int t = blockIdx.x;
  int c = threadIdx.x * 4;
  int p0 = tok_pos[t * 2], p1 = tok_pos[t * 2 + 1];
  float w0 = topk_w[t * 2], w1 = topk_w[t * 2 + 1];
  const float* h1 = po + (size_t)P * HD;
  float4 a0 = *(const float4*)&po[(size_t)p0 * HD + c];
  float4 a1 = *(const float4*)&h1[(size_t)p0 * HD + c];
  float4 b0 = *(const float4*)&po[(size_t)p1 * HD + c];
  float4 b1 = *(const float4*)&h1[(size_t)p1 * HD + c];
  float4 o;
  o.x = w0 * (a0.x + a1.x) + w1 * (b0.x + b1.x);
  o.y = w0 * (a0.y + a1.y) + w1 * (b0.y + b1.y);
  o.z = w0 * (a0.z + a1.z) + w1 * (b0.z + b1.z);
  o.w = w0 * (a0.w + a1.w) + w1 * (b0.w + b1.w);
  *(float4*)&out[(size_t)t * HD + c] = o;
}

extern "C" void kernel_launch(void* const* d_in, const int* in_sizes, int n_in,
                              void* d_out, int out_size, void* d_ws, size_t ws_size,
                              hipStream_t stream) {
  const float* x      = (const float*)d_in[0];
  const float* gate_w = (const float*)d_in[1];
  const float* w1     = (const float*)d_in[2];
  const float* b1     = (const float*)d_in[3];
  const float* w2     = (const float*)d_in[4];
  const float* b2     = (const float*)d_in[5];
  float* out = (float*)d_out;
  (void)in_sizes; (void)n_in; (void)out_size; (void)ws_size;

  char* w = (char*)d_ws;
  size_t off = 0;
  auto alloc = [&](size_t bytes) -> void* {
    void* p = w + off;
    off = (off + bytes + 255) & ~(size_t)255;
    return p;
  };
  int*      meta     = (int*)alloc(256);
  int*      fill     = meta;
  int*      offsets  = (int*)alloc(256);
  int*      ntiles   = offsets + 8;
  TileDesc* desc     = (TileDesc*)alloc(sizeof(TileDesc) * 128);
  int*      topk_idx = (int*)alloc(sizeof(int) * P);
  float*    topk_w   = (float*)alloc(sizeof(float) * P);
  int*      tok_pos  = (int*)alloc(sizeof(int) * P);
  int*      pair_tok = (int*)alloc(sizeof(int) * PPAD);
  float*    psums    = (float*)alloc(sizeof(float) * RNB * NE);
  int*      pcounts  = (int*)alloc(sizeof(int) * RNB * NE);
  uint16_t* xb       = (uint16_t*)alloc((size_t)T * HD * 2);
  uint16_t* w1t      = (uint16_t*)alloc((size_t)NE * FD * HD * 2);   // 64 MiB
  uint16_t* w2t      = (uint16_t*)alloc((size_t)NE * HD * FD * 2);
  uint16_t* hidden   = (uint16_t*)alloc((size_t)PPAD * FD * 2);
  // fc2 fp32 partial outputs (2 x P*HD floats = 64 MiB) alias the w1t region:
  // w1t is dead once fc1 completes, and fc2 runs strictly after fc1 (same stream).
  float*    pout     = (float*)w1t;

  hipMemsetAsync(meta, 0, 256, stream);
  cvt_x_kernel<<<(T * HD) / 1024, 256, 0, stream>>>(x, xb);
  transpose_cvt_kernel<<<dim3(FD / 64, HD / 64, NE), 256, 0, stream>>>(w1, w1t, HD, FD);
  transpose_cvt_kernel<<<dim3(HD / 64, FD / 64, NE), 256, 0, stream>>>(w2, w2t, FD, HD);
  router_kernel<<<RNB, 256, 0, stream>>>(x, gate_w, topk_idx, topk_w, psums, pcounts);
  finalize_kernel<<<1, 64, 0, stream>>>(pcounts, psums, offsets, desc, ntiles,
                                        out + (size_t)T * HD);
  scatter_kernel<<<T / 256, 256, 0, stream>>>(topk_idx, offsets, fill, pair_tok, tok_pos);
  // fc1: KSTRIDE=KLEN=1024, gather+relu, bf16 out; grid 32nb*72mt = 2304
  moe_gemm<HD, HD, FD, 4, 1, 0><<<(FD / 128) * MAXT, 256, 0, stream>>>(
      xb, pair_tok, w1t, b1, hidden, desc, ntiles);
  // fc2: KSTRIDE=4096, KLEN=2048, 2-way K-split, fp32 partials; grid 8nb*72mt*2 = 1152
  moe_gemm<FD, FD / 2, HD, 8, 2, 1><<<(HD / 128) * MAXT * 2, 256, 0, stream>>>(
      hidden, nullptr, w2t, b2, pout, desc, ntiles);
  combine_kernel<<<T, 256, 0, stream>>>(pout, tok_pos, topk_w, out);
}